// Round 10
// baseline (1123.495 us; speedup 1.0000x reference)
//
#include <hip/hip_runtime.h>

// GCN: 3-layer graph conv, N=100000 nodes, E=3.2M edges, feats 256->256->256->64.
// R21 = R20 (verified 1101.8us) + visibility + gemm A-prefetch:
//  (a) spmm_bf16row quarter-split (4 dispatches/pass, ~58us each): top-5 only
//      ever shows the heaviest kernel type (dispatches repeat across bench
//      iters); ~640us of pipeline hides below the 115us curtain. Known split
//      cost ~+10-20us, buys per-kernel counters for the whole second tier.
//  (b) gemm_f32a A-prefetch: kk+1's A float4s issued between W-staging and the
//      second barrier -> A-load (L3/HBM ~500cy) retires under stage+barrier+MFMA
//      instead of serializing after the barrier. Same values/order: bit-identical.
// u8 prep (R20), spmm loop body (R15-proven), GEMM 8-wave structure unchanged.

typedef __bf16  bf16x8 __attribute__((ext_vector_type(8)));
typedef float   f32x4  __attribute__((ext_vector_type(4)));

#define FEATS 256
#define NRANGE 2
#define RSZ 50000      // nodes per range; 2*50000 = 100000 = nN
#define NSLICE 128

static __device__ __forceinline__ unsigned short f2bf(float f) {
  unsigned u = __float_as_uint(f);
  u += 0x7fffu + ((u >> 16) & 1u);          // round-to-nearest-even
  return (unsigned short)(u >> 16);
}
static __device__ __forceinline__ float bfval(unsigned short h) { return __uint_as_float((unsigned)h << 16); }
static __device__ __forceinline__ float bflo(unsigned u) { return __uint_as_float(u << 16); }
static __device__ __forceinline__ float bfhi(unsigned u) { return __uint_as_float(u & 0xffff0000u); }

// ---------------- graph prep: u8 LDS histograms ----------------

__global__ void hist_u8(const int* __restrict__ idx, unsigned char* __restrict__ P,
                        int nE, int nN, int chunk) {
  __shared__ unsigned cnt[RSZ / 4];
  const int s = blockIdx.x, r = blockIdx.y;
  const int r0 = r * RSZ;
  for (int t = threadIdx.x; t < RSZ / 4; t += 256) cnt[t] = 0u;
  __syncthreads();
  int lo = s * chunk;
  int hi = lo + chunk; if (hi > nE) hi = nE;
  for (int i = lo + threadIdx.x; i < hi; i += 256) {
    int n = idx[i] - r0;
    if ((unsigned)n < (unsigned)RSZ)
      atomicAdd(&cnt[n >> 2], 1u << ((n & 3) * 8));
  }
  __syncthreads();
  unsigned* Pw = (unsigned*)(P + (size_t)s * nN + r0);   // s*nN, r0 both %4==0
  for (int t = threadIdx.x; t < RSZ / 4; t += 256) {
    if (r0 + t * 4 < nN) Pw[t] = cnt[t];
  }
}

__global__ void reduce_prefix_norms(unsigned char* __restrict__ Pin, const unsigned char* __restrict__ Pout,
                                    unsigned* __restrict__ indeg, float* __restrict__ snorm,
                                    float* __restrict__ dnorm, int nN) {
  int n = blockIdx.x * blockDim.x + threadIdx.x;
  if (n >= nN) return;
  unsigned cin = 0u, cout = 0u;
  for (int s = 0; s < NSLICE; ++s) {
    size_t o = (size_t)s * nN + n;
    unsigned v = Pin[o];
    Pin[o] = (unsigned char)cin;     // prefix <= indeg <= ~70, fits u8
    cin += v;
    cout += Pout[o];
  }
  indeg[n] = cin;
  unsigned id = cin < 1u ? 1u : cin;
  unsigned od = cout < 1u ? 1u : cout;
  dnorm[n] = 1.0f / sqrtf((float)id);
  snorm[n] = 1.0f / sqrtf((float)od);
}

__global__ void place_u8(const int* __restrict__ src, const int* __restrict__ dst,
                         const unsigned char* __restrict__ Ppfx, const unsigned* __restrict__ row_ptr,
                         unsigned* __restrict__ edge_src, int nE, int nN, int chunk) {
  __shared__ unsigned cnt[RSZ / 4];
  const int s = blockIdx.x, r = blockIdx.y;
  const int r0 = r * RSZ;
  for (int t = threadIdx.x; t < RSZ / 4; t += 256) cnt[t] = 0u;
  __syncthreads();
  const unsigned char* Ps = Ppfx + (size_t)s * nN;
  int lo = s * chunk;
  int hi = lo + chunk; if (hi > nE) hi = nE;
  for (int i = lo + threadIdx.x; i < hi; i += 256) {
    int d = dst[i];
    int n = d - r0;
    if ((unsigned)n < (unsigned)RSZ) {
      int sh = (n & 3) * 8;
      unsigned old = atomicAdd(&cnt[n >> 2], 1u << sh);
      unsigned lr = (old >> sh) & 0xffu;
      unsigned pos = row_ptr[d] + (unsigned)Ps[d] + lr;
      edge_src[pos] = (unsigned)src[i];
    }
  }
}

// Xb[n][c] = bf16(feat[n][c] * snorm[n]); thread handles 8 elems
__global__ void prescale_bf16(const float* __restrict__ feat, const float* __restrict__ snorm,
                              unsigned short* __restrict__ Xb, int total8 /* nN*32 */) {
  int i8 = blockIdx.x * blockDim.x + threadIdx.x;
  if (i8 >= total8) return;
  float4 u = ((const float4*)feat)[i8 * 2];
  float4 v = ((const float4*)feat)[i8 * 2 + 1];
  float s = snorm[i8 >> 5];
  uint2 a, b;
  a.x = (unsigned)f2bf(u.x * s) | ((unsigned)f2bf(u.y * s) << 16);
  a.y = (unsigned)f2bf(u.z * s) | ((unsigned)f2bf(u.w * s) << 16);
  b.x = (unsigned)f2bf(v.x * s) | ((unsigned)f2bf(v.y * s) << 16);
  b.y = (unsigned)f2bf(v.z * s) | ((unsigned)f2bf(v.w * s) << 16);
  *(uint4*)(Xb + (size_t)i8 * 8) = make_uint4(a.x, a.y, b.x, b.y);
}

// ---------------- CSR row_ptr scan ----------------

__global__ void scan_blocks(const unsigned* __restrict__ in, unsigned* __restrict__ excl,
                            unsigned* __restrict__ partials, int n) {
  __shared__ unsigned tmp[1024];
  int t = threadIdx.x;
  int g = blockIdx.x * 1024 + t;
  unsigned v = (g < n) ? in[g] : 0u;
  tmp[t] = v;
  __syncthreads();
  for (int off = 1; off < 1024; off <<= 1) {
    unsigned add = (t >= off) ? tmp[t - off] : 0u;
    __syncthreads();
    tmp[t] += add;
    __syncthreads();
  }
  if (g < n) excl[g] = tmp[t] - v;
  if (t == 1023) partials[blockIdx.x] = tmp[t];
}

__global__ void scan_partials(unsigned* __restrict__ partials, int nb) {
  __shared__ unsigned tmp[1024];
  int t = threadIdx.x;
  unsigned v = (t < nb) ? partials[t] : 0u;
  tmp[t] = v;
  __syncthreads();
  for (int off = 1; off < 1024; off <<= 1) {
    unsigned add = (t >= off) ? tmp[t - off] : 0u;
    __syncthreads();
    tmp[t] += add;
    __syncthreads();
  }
  if (t < nb) partials[t] = tmp[t] - v;   // exclusive
}

__global__ void finalize_rowptr(const unsigned* __restrict__ excl, const unsigned* __restrict__ partials,
                                unsigned* __restrict__ row_ptr, int n, int nE) {
  int g = blockIdx.x * blockDim.x + threadIdx.x;
  if (g < n) row_ptr[g] = excl[g] + partials[g >> 10];
  if (g == 0) row_ptr[n] = (unsigned)nE;
}

// ---------------- weight split (hi/lo, transposed) ----------------

__global__ void cast_w_split(const float* __restrict__ W, unsigned short* __restrict__ Wh,
                             unsigned short* __restrict__ Wl, int K, int N) {
  int i = blockIdx.x * blockDim.x + threadIdx.x;
  if (i < K * N) {
    int n = i / K, k = i - n * K;
    float v = W[k * N + n];
    unsigned short h = f2bf(v);
    Wh[i] = h;
    Wl[i] = f2bf(v - bfval(h));
  }
}

// ---------------- SpMM (CSR gather) — PROVEN loop, dst-quarter partition ----------------

// bf16 input: G[d][c] = dnorm[d] * sum_{e: dst=d} Xb[src_e][c]; fp32 accum/out
__global__ void spmm_bf16row(const unsigned short* __restrict__ Xb, const unsigned* __restrict__ row_ptr,
                             const unsigned* __restrict__ edge_src, const float* __restrict__ dnorm,
                             float* __restrict__ G, int lo, int hi) {
  int wid  = lo + ((blockIdx.x * blockDim.x + threadIdx.x) >> 6);
  int lane = threadIdx.x & 63;
  if (wid >= hi) return;
  unsigned start = row_ptr[wid];
  int cnt = (int)(row_ptr[wid + 1] - start);
  float a0 = 0.f, a1 = 0.f, a2 = 0.f, a3 = 0.f;
  int colbase = lane * 4;
  for (int base = 0; base < cnt; base += 64) {
    int m = cnt - base; if (m > 64) m = 64;
    unsigned myidx = (lane < m) ? edge_src[start + base + lane] : 0u;
    int e = 0;
    for (; e + 1 < m; e += 2) {
      unsigned s0 = __shfl(myidx, e);
      unsigned s1 = __shfl(myidx, e + 1);
      uint2 d0 = *(const uint2*)(Xb + (size_t)s0 * FEATS + colbase);
      uint2 d1 = *(const uint2*)(Xb + (size_t)s1 * FEATS + colbase);
      a0 += bflo(d0.x); a1 += bfhi(d0.x); a2 += bflo(d0.y); a3 += bfhi(d0.y);
      a0 += bflo(d1.x); a1 += bfhi(d1.x); a2 += bflo(d1.y); a3 += bfhi(d1.y);
    }
    if (e < m) {
      unsigned s0 = __shfl(myidx, e);
      uint2 d0 = *(const uint2*)(Xb + (size_t)s0 * FEATS + colbase);
      a0 += bflo(d0.x); a1 += bfhi(d0.x); a2 += bflo(d0.y); a3 += bfhi(d0.y);
    }
  }
  float sc = dnorm[wid];
  *(float4*)(G + (size_t)wid * FEATS + colbase) =
      make_float4(a0 * sc, a1 * sc, a2 * sc, a3 * sc);
}

// 64-dim bf16 input: lane = column, all lanes iterate all edges; fp32 accum; fp32 out
__global__ void spmm64_bf16(const unsigned short* __restrict__ Xb, const unsigned* __restrict__ row_ptr,
                            const unsigned* __restrict__ edge_src, const float* __restrict__ dnorm,
                            float* __restrict__ out, int nN) {
  int wid  = (blockIdx.x * blockDim.x + threadIdx.x) >> 6;
  int lane = threadIdx.x & 63;
  if (wid >= nN) return;
  unsigned start = row_ptr[wid];
  int cnt = (int)(row_ptr[wid + 1] - start);
  float a0 = 0.f;
  for (int base = 0; base < cnt; base += 64) {
    int m = cnt - base; if (m > 64) m = 64;
    unsigned myidx = (lane < m) ? edge_src[start + base + lane] : 0u;
    int e = 0;
    for (; e + 1 < m; e += 2) {
      unsigned s0 = __shfl(myidx, e);
      unsigned s1 = __shfl(myidx, e + 1);
      a0 += bfval(Xb[(size_t)s0 * 64 + lane]);
      a0 += bfval(Xb[(size_t)s1 * 64 + lane]);
    }
    if (e < m) {
      unsigned s0 = __shfl(myidx, e);
      a0 += bfval(Xb[(size_t)s0 * 64 + lane]);
    }
  }
  out[(size_t)wid * 64 + lane] = a0 * dnorm[wid];
}

// ---------------- GEMM: MFMA, 8 waves x 1 strip, A-prefetch, 3-term ----------------

static __device__ __forceinline__ void split8v(float4 u, float4 v, bf16x8& h, bf16x8& l) {
  float x[8] = {u.x, u.y, u.z, u.w, v.x, v.y, v.z, v.w};
#pragma unroll
  for (int j = 0; j < 8; ++j) {
    __bf16 hh = (__bf16)x[j];
    h[j] = hh;
    l[j] = (__bf16)(x[j] - (float)hh);
  }
}

static __device__ __forceinline__ void storev(unsigned short* p, float v) { *p = f2bf(v); }
static __device__ __forceinline__ void storev(float* p, float v) { *p = v; }

template<int NT, bool RELU, bool SCALE, typename OutT>
__global__ __launch_bounds__(512, 4)
void gemm_f32a(const float* __restrict__ A,
               const unsigned short* __restrict__ Wh, const unsigned short* __restrict__ Wl,
               const float* __restrict__ snorm, OutT* __restrict__ out, int nN) {
  __shared__ unsigned short Bh[NT * 512];   // [nt][lane][8] bf16, frag-linear
  __shared__ unsigned short Bl[NT * 512];
  const int tid  = threadIdx.x;
  const int w    = tid >> 6;            // 0..7
  const int lane = tid & 63;
  const int quad = lane >> 4;
  const int l16  = lane & 15;
  const int m0   = blockIdx.x * 128 + w * 16;   // one 16-row strip per wave

  f32x4 acc[NT];
#pragma unroll
  for (int i = 0; i < NT; ++i) acc[i] = (f32x4){0.f, 0.f, 0.f, 0.f};

  int r0 = m0 + l16;  int rc0 = (r0 < nN) ? r0 : (nN - 1);
  const float* Ap = A + (size_t)rc0 * 256 + quad * 8;

  float4 u = *(const float4*)(Ap);          // prefetch kk=0
  float4 v = *(const float4*)(Ap + 4);

  for (int kk = 0; kk < 8; ++kk) {
    __syncthreads();
    for (int ch = tid; ch < NT * 64; ch += 512) {
      int nt = ch >> 6; int L = ch & 63;
      int n  = nt * 16 + (L & 15);
      int kb = (L >> 4) * 8;
      *(int4*)(Bh + ch * 8) = *(const int4*)(Wh + n * 256 + kk * 32 + kb);
      *(int4*)(Bl + ch * 8) = *(const int4*)(Wl + n * 256 + kk * 32 + kb);
    }
    // issue next kk's A-load before the barrier: retires under barrier + MFMA
    float4 un = u, vn = v;
    if (kk < 7) {
      un = *(const float4*)(Ap + (kk + 1) * 32);
      vn = *(const float4*)(Ap + (kk + 1) * 32 + 4);
    }
    __syncthreads();
    bf16x8 ah, al;
    split8v(u, v, ah, al);
#pragma unroll
    for (int nt = 0; nt < NT; ++nt) {
      bf16x8 bh = *(const bf16x8*)(Bh + nt * 512 + lane * 8);
      bf16x8 bl = *(const bf16x8*)(Bl + nt * 512 + lane * 8);
      acc[nt] = __builtin_amdgcn_mfma_f32_16x16x32_bf16(ah, bh, acc[nt], 0, 0, 0);
      acc[nt] = __builtin_amdgcn_mfma_f32_16x16x32_bf16(al, bh, acc[nt], 0, 0, 0);
      acc[nt] = __builtin_amdgcn_mfma_f32_16x16x32_bf16(ah, bl, acc[nt], 0, 0, 0);
    }
    u = un; v = vn;
  }

  // epilogue: C/D layout col=lane&15, row=quad*4+reg
  const int N = NT * 16;
#pragma unroll
  for (int reg = 0; reg < 4; ++reg) {
    int rr0 = m0 + quad * 4 + reg;
    float s0 = 1.f;
    if (SCALE) s0 = snorm[(rr0 < nN) ? rr0 : 0];
#pragma unroll
    for (int nt = 0; nt < NT; ++nt) {
      if (rr0 < nN) {
        float v2 = acc[nt][reg];
        if (RELU) v2 = fmaxf(v2, 0.f);
        if (SCALE) v2 *= s0;
        storev(out + (size_t)rr0 * N + nt * 16 + l16, v2);
      }
    }
  }
}

// ---------------- launch ----------------

extern "C" void kernel_launch(void* const* d_in, const int* in_sizes, int n_in,
                              void* d_out, int out_size, void* d_ws, size_t ws_size,
                              hipStream_t stream) {
  const float* feat = (const float*)d_in[0];
  const int*   src  = (const int*)d_in[1];
  const int*   dst  = (const int*)d_in[2];
  const float* W0   = (const float*)d_in[3];
  const float* W1   = (const float*)d_in[4];
  const float* W2   = (const float*)d_in[5];
  const int nE = in_sizes[1];
  const int nN = in_sizes[0] / FEATS;

  char* p = (char*)d_ws;
  auto alloc = [&](size_t bytes) -> void* {
    void* r = (void*)p;
    p += (bytes + 255) & ~(size_t)255;
    return r;
  };
  unsigned* outdeg = (unsigned*)alloc((size_t)nN * 4);   // pure W-plane space
  unsigned* indeg  = (unsigned*)alloc((size_t)nN * 4);
  float*    snorm  = (float*)   alloc((size_t)nN * 4);
  float*    dnorm  = (float*)   alloc((size_t)nN * 4);
  float*    X      = (float*)   alloc((size_t)nN * 256 * 4);  // bf16 X1/F1; fp32 F2
  float*    G      = (float*)   alloc((size_t)nN * 256 * 4);  // agg buffer; P_in/P_out/H3b alias
  unsigned* excl     = (unsigned*)alloc((size_t)nN * 4);
  unsigned* partials = (unsigned*)alloc(1024 * 4);
  unsigned* row_ptr  = (unsigned*)alloc(((size_t)nN + 1) * 4);
  unsigned* edge_src = (unsigned*)alloc((size_t)nE * 4);
  // footprint < proven 220.0 MB

  unsigned short* Xb  = (unsigned short*)X;   // bf16 view (first half of X region)
  unsigned char* P_in  = (unsigned char*)G;   // u8 planes, dead before spmm layer 1
  unsigned char* P_out = P_in + (size_t)NSLICE * nN;
  unsigned short* H3b = (unsigned short*)G;   // layer-3 bf16 output (12.8MB), alias ok

  // Weight hi/lo planes (576 KB) alias the dead outdeg/indeg region (proven R9/R10)
  unsigned short* W0h = (unsigned short*)outdeg;
  unsigned short* W0l = W0h + 256 * 256;
  unsigned short* W1h = W0l + 256 * 256;
  unsigned short* W1l = W1h + 256 * 256;
  unsigned short* W2h = W1l + 256 * 256;
  unsigned short* W2l = W2h + 64 * 256;

  const int TB = 256;
  int gN  = (nN + TB - 1) / TB;
  int nb  = (nN + 1023) / 1024;
  int gRow = (nN * 64 + TB - 1) / TB;   // wave per row/node (full range)
  int gGm  = (nN + 127) / 128;          // MFMA gemm: 128 rows/block, 512 threads
  int chunk = (nE + NSLICE - 1) / NSLICE;
  dim3 gHist(NSLICE, NRANGE);

  // u8 atomic-free graph prep
  hist_u8<<<gHist, TB, 0, stream>>>(dst, P_in,  nE, nN, chunk);
  hist_u8<<<gHist, TB, 0, stream>>>(src, P_out, nE, nN, chunk);
  reduce_prefix_norms<<<gN, TB, 0, stream>>>(P_in, P_out, indeg, snorm, dnorm, nN);
  scan_blocks<<<nb, 1024, 0, stream>>>(indeg, excl, partials, nN);
  scan_partials<<<1, 1024, 0, stream>>>(partials, nb);
  finalize_rowptr<<<gN, TB, 0, stream>>>(excl, partials, row_ptr, nN, nE);
  place_u8<<<gHist, TB, 0, stream>>>(src, dst, P_in, row_ptr, edge_src, nE, nN, chunk);

  // weight splits into the dead outdeg/indeg region
  cast_w_split<<<(256 * 256 + TB - 1) / TB, TB, 0, stream>>>(W0, W0h, W0l, 256, 256);
  cast_w_split<<<(256 * 256 + TB - 1) / TB, TB, 0, stream>>>(W1, W1h, W1l, 256, 256);
  cast_w_split<<<(256 * 64  + TB - 1) / TB, TB, 0, stream>>>(W2, W2h, W2l, 256, 64);

  int total8 = nN * (FEATS / 8);
  prescale_bf16<<<(total8 + TB - 1) / TB, TB, 0, stream>>>(feat, snorm, Xb, total8);

  int q = (nN + 3) / 4;   // spmm dst-quarter bounds

  // layer 1: G = dn * seg_sum(Xb[src]); F1 = bf16(relu(G @ W0)*sn) -> Xb
  for (int i = 0; i < 4; ++i) {
    int lo = i * q, hi = (lo + q < nN) ? lo + q : nN;
    int g = ((hi - lo) * 64 + TB - 1) / TB;
    spmm_bf16row<<<g, TB, 0, stream>>>(Xb, row_ptr, edge_src, dnorm, G, lo, hi);
  }
  gemm_f32a<16, true, true, unsigned short><<<gGm, 512, 0, stream>>>(G, W0h, W0l, snorm, Xb, nN);
  // layer 2: bf16 gather -> G fp32; F2 = fp32 relu(G @ W1)*sn -> X
  for (int i = 0; i < 4; ++i) {
    int lo = i * q, hi = (lo + q < nN) ? lo + q : nN;
    int g = ((hi - lo) * 64 + TB - 1) / TB;
    spmm_bf16row<<<g, TB, 0, stream>>>(Xb, row_ptr, edge_src, dnorm, G, lo, hi);
  }
  gemm_f32a<16, true, true, float><<<gGm, 512, 0, stream>>>(G, W1h, W1l, snorm, X, nN);
  // layer 3: H3b = bf16(X @ W2) -> G region; out = dn * seg_sum(H3b[src]) in fp32
  gemm_f32a<4, false, false, unsigned short><<<gGm, 512, 0, stream>>>(X, W2h, W2l, nullptr, H3b, nN);
  spmm64_bf16<<<gRow, TB, 0, stream>>>(H3b, row_ptr, edge_src, dnorm, (float*)d_out, nN);
}

// Round 11
// 1068.661 us; speedup vs baseline: 1.0513x; 1.0513x over previous
//
#include <hip/hip_runtime.h>

// GCN: 3-layer graph conv, N=100000 nodes, E=3.2M edges, feats 256->256->256->64.
// R22 = R21 with: (a) spmm quarter-split reverted to halves (split cost ~20us,
// visibility job done); (b) spmm64 4-deep ORDER-PRESERVING unroll (R17's exact
// body, which passed at 2^-10) -- spmm64 counters show 22% HBM BW + 34% VALU =
// latency-bound, 2 loads in flight; 4-deep doubles MLP. The R12 lane-remap
// restructures stay parked (failed absmax, unexplained).
// (c) gemm A-prefetch kept (R21, theory-sound, now unconfounded).
// u8 prep (R20-verified), spmm_bf16row body (R15-proven) unchanged.

typedef __bf16  bf16x8 __attribute__((ext_vector_type(8)));
typedef float   f32x4  __attribute__((ext_vector_type(4)));

#define FEATS 256
#define NRANGE 2
#define RSZ 50000      // nodes per range; 2*50000 = 100000 = nN
#define NSLICE 128

static __device__ __forceinline__ unsigned short f2bf(float f) {
  unsigned u = __float_as_uint(f);
  u += 0x7fffu + ((u >> 16) & 1u);          // round-to-nearest-even
  return (unsigned short)(u >> 16);
}
static __device__ __forceinline__ float bfval(unsigned short h) { return __uint_as_float((unsigned)h << 16); }
static __device__ __forceinline__ float bflo(unsigned u) { return __uint_as_float(u << 16); }
static __device__ __forceinline__ float bfhi(unsigned u) { return __uint_as_float(u & 0xffff0000u); }

// ---------------- graph prep: u8 LDS histograms ----------------

__global__ void hist_u8(const int* __restrict__ idx, unsigned char* __restrict__ P,
                        int nE, int nN, int chunk) {
  __shared__ unsigned cnt[RSZ / 4];
  const int s = blockIdx.x, r = blockIdx.y;
  const int r0 = r * RSZ;
  for (int t = threadIdx.x; t < RSZ / 4; t += 256) cnt[t] = 0u;
  __syncthreads();
  int lo = s * chunk;
  int hi = lo + chunk; if (hi > nE) hi = nE;
  for (int i = lo + threadIdx.x; i < hi; i += 256) {
    int n = idx[i] - r0;
    if ((unsigned)n < (unsigned)RSZ)
      atomicAdd(&cnt[n >> 2], 1u << ((n & 3) * 8));
  }
  __syncthreads();
  unsigned* Pw = (unsigned*)(P + (size_t)s * nN + r0);   // s*nN, r0 both %4==0
  for (int t = threadIdx.x; t < RSZ / 4; t += 256) {
    if (r0 + t * 4 < nN) Pw[t] = cnt[t];
  }
}

__global__ void reduce_prefix_norms(unsigned char* __restrict__ Pin, const unsigned char* __restrict__ Pout,
                                    unsigned* __restrict__ indeg, float* __restrict__ snorm,
                                    float* __restrict__ dnorm, int nN) {
  int n = blockIdx.x * blockDim.x + threadIdx.x;
  if (n >= nN) return;
  unsigned cin = 0u, cout = 0u;
  for (int s = 0; s < NSLICE; ++s) {
    size_t o = (size_t)s * nN + n;
    unsigned v = Pin[o];
    Pin[o] = (unsigned char)cin;     // prefix <= indeg <= ~70, fits u8
    cin += v;
    cout += Pout[o];
  }
  indeg[n] = cin;
  unsigned id = cin < 1u ? 1u : cin;
  unsigned od = cout < 1u ? 1u : cout;
  dnorm[n] = 1.0f / sqrtf((float)id);
  snorm[n] = 1.0f / sqrtf((float)od);
}

__global__ void place_u8(const int* __restrict__ src, const int* __restrict__ dst,
                         const unsigned char* __restrict__ Ppfx, const unsigned* __restrict__ row_ptr,
                         unsigned* __restrict__ edge_src, int nE, int nN, int chunk) {
  __shared__ unsigned cnt[RSZ / 4];
  const int s = blockIdx.x, r = blockIdx.y;
  const int r0 = r * RSZ;
  for (int t = threadIdx.x; t < RSZ / 4; t += 256) cnt[t] = 0u;
  __syncthreads();
  const unsigned char* Ps = Ppfx + (size_t)s * nN;
  int lo = s * chunk;
  int hi = lo + chunk; if (hi > nE) hi = nE;
  for (int i = lo + threadIdx.x; i < hi; i += 256) {
    int d = dst[i];
    int n = d - r0;
    if ((unsigned)n < (unsigned)RSZ) {
      int sh = (n & 3) * 8;
      unsigned old = atomicAdd(&cnt[n >> 2], 1u << sh);
      unsigned lr = (old >> sh) & 0xffu;
      unsigned pos = row_ptr[d] + (unsigned)Ps[d] + lr;
      edge_src[pos] = (unsigned)src[i];
    }
  }
}

// Xb[n][c] = bf16(feat[n][c] * snorm[n]); thread handles 8 elems
__global__ void prescale_bf16(const float* __restrict__ feat, const float* __restrict__ snorm,
                              unsigned short* __restrict__ Xb, int total8 /* nN*32 */) {
  int i8 = blockIdx.x * blockDim.x + threadIdx.x;
  if (i8 >= total8) return;
  float4 u = ((const float4*)feat)[i8 * 2];
  float4 v = ((const float4*)feat)[i8 * 2 + 1];
  float s = snorm[i8 >> 5];
  uint2 a, b;
  a.x = (unsigned)f2bf(u.x * s) | ((unsigned)f2bf(u.y * s) << 16);
  a.y = (unsigned)f2bf(u.z * s) | ((unsigned)f2bf(u.w * s) << 16);
  b.x = (unsigned)f2bf(v.x * s) | ((unsigned)f2bf(v.y * s) << 16);
  b.y = (unsigned)f2bf(v.z * s) | ((unsigned)f2bf(v.w * s) << 16);
  *(uint4*)(Xb + (size_t)i8 * 8) = make_uint4(a.x, a.y, b.x, b.y);
}

// ---------------- CSR row_ptr scan ----------------

__global__ void scan_blocks(const unsigned* __restrict__ in, unsigned* __restrict__ excl,
                            unsigned* __restrict__ partials, int n) {
  __shared__ unsigned tmp[1024];
  int t = threadIdx.x;
  int g = blockIdx.x * 1024 + t;
  unsigned v = (g < n) ? in[g] : 0u;
  tmp[t] = v;
  __syncthreads();
  for (int off = 1; off < 1024; off <<= 1) {
    unsigned add = (t >= off) ? tmp[t - off] : 0u;
    __syncthreads();
    tmp[t] += add;
    __syncthreads();
  }
  if (g < n) excl[g] = tmp[t] - v;
  if (t == 1023) partials[blockIdx.x] = tmp[t];
}

__global__ void scan_partials(unsigned* __restrict__ partials, int nb) {
  __shared__ unsigned tmp[1024];
  int t = threadIdx.x;
  unsigned v = (t < nb) ? partials[t] : 0u;
  tmp[t] = v;
  __syncthreads();
  for (int off = 1; off < 1024; off <<= 1) {
    unsigned add = (t >= off) ? tmp[t - off] : 0u;
    __syncthreads();
    tmp[t] += add;
    __syncthreads();
  }
  if (t < nb) partials[t] = tmp[t] - v;   // exclusive
}

__global__ void finalize_rowptr(const unsigned* __restrict__ excl, const unsigned* __restrict__ partials,
                                unsigned* __restrict__ row_ptr, int n, int nE) {
  int g = blockIdx.x * blockDim.x + threadIdx.x;
  if (g < n) row_ptr[g] = excl[g] + partials[g >> 10];
  if (g == 0) row_ptr[n] = (unsigned)nE;
}

// ---------------- weight split (hi/lo, transposed) ----------------

__global__ void cast_w_split(const float* __restrict__ W, unsigned short* __restrict__ Wh,
                             unsigned short* __restrict__ Wl, int K, int N) {
  int i = blockIdx.x * blockDim.x + threadIdx.x;
  if (i < K * N) {
    int n = i / K, k = i - n * K;
    float v = W[k * N + n];
    unsigned short h = f2bf(v);
    Wh[i] = h;
    Wl[i] = f2bf(v - bfval(h));
  }
}

// ---------------- SpMM (CSR gather) — PROVEN loop, dst-half partition ----------------

// bf16 input: G[d][c] = dnorm[d] * sum_{e: dst=d} Xb[src_e][c]; fp32 accum/out
__global__ void spmm_bf16row(const unsigned short* __restrict__ Xb, const unsigned* __restrict__ row_ptr,
                             const unsigned* __restrict__ edge_src, const float* __restrict__ dnorm,
                             float* __restrict__ G, int lo, int hi) {
  int wid  = lo + ((blockIdx.x * blockDim.x + threadIdx.x) >> 6);
  int lane = threadIdx.x & 63;
  if (wid >= hi) return;
  unsigned start = row_ptr[wid];
  int cnt = (int)(row_ptr[wid + 1] - start);
  float a0 = 0.f, a1 = 0.f, a2 = 0.f, a3 = 0.f;
  int colbase = lane * 4;
  for (int base = 0; base < cnt; base += 64) {
    int m = cnt - base; if (m > 64) m = 64;
    unsigned myidx = (lane < m) ? edge_src[start + base + lane] : 0u;
    int e = 0;
    for (; e + 1 < m; e += 2) {
      unsigned s0 = __shfl(myidx, e);
      unsigned s1 = __shfl(myidx, e + 1);
      uint2 d0 = *(const uint2*)(Xb + (size_t)s0 * FEATS + colbase);
      uint2 d1 = *(const uint2*)(Xb + (size_t)s1 * FEATS + colbase);
      a0 += bflo(d0.x); a1 += bfhi(d0.x); a2 += bflo(d0.y); a3 += bfhi(d0.y);
      a0 += bflo(d1.x); a1 += bfhi(d1.x); a2 += bflo(d1.y); a3 += bfhi(d1.y);
    }
    if (e < m) {
      unsigned s0 = __shfl(myidx, e);
      uint2 d0 = *(const uint2*)(Xb + (size_t)s0 * FEATS + colbase);
      a0 += bflo(d0.x); a1 += bfhi(d0.x); a2 += bflo(d0.y); a3 += bfhi(d0.y);
    }
  }
  float sc = dnorm[wid];
  *(float4*)(G + (size_t)wid * FEATS + colbase) =
      make_float4(a0 * sc, a1 * sc, a2 * sc, a3 * sc);
}

// 64-dim bf16 input: lane = column; 4-deep order-preserving unroll (R17-proven).
__global__ void spmm64_bf16(const unsigned short* __restrict__ Xb, const unsigned* __restrict__ row_ptr,
                            const unsigned* __restrict__ edge_src, const float* __restrict__ dnorm,
                            float* __restrict__ out, int nN) {
  int wid  = (blockIdx.x * blockDim.x + threadIdx.x) >> 6;
  int lane = threadIdx.x & 63;
  if (wid >= nN) return;
  unsigned start = row_ptr[wid];
  int cnt = (int)(row_ptr[wid + 1] - start);
  float a0 = 0.f;
  for (int base = 0; base < cnt; base += 64) {
    int m = cnt - base; if (m > 64) m = 64;
    unsigned myidx = (lane < m) ? edge_src[start + base + lane] : 0u;
    int e = 0;
    for (; e + 3 < m; e += 4) {
      unsigned s0 = __shfl(myidx, e);
      unsigned s1 = __shfl(myidx, e + 1);
      unsigned s2 = __shfl(myidx, e + 2);
      unsigned s3 = __shfl(myidx, e + 3);
      float v0 = bfval(Xb[(size_t)s0 * 64 + lane]);
      float v1 = bfval(Xb[(size_t)s1 * 64 + lane]);
      float v2 = bfval(Xb[(size_t)s2 * 64 + lane]);
      float v3 = bfval(Xb[(size_t)s3 * 64 + lane]);
      a0 += v0; a0 += v1; a0 += v2; a0 += v3;
    }
    for (; e < m; ++e) {
      unsigned s0 = __shfl(myidx, e);
      a0 += bfval(Xb[(size_t)s0 * 64 + lane]);
    }
  }
  out[(size_t)wid * 64 + lane] = a0 * dnorm[wid];
}

// ---------------- GEMM: MFMA, 8 waves x 1 strip, A-prefetch, 3-term ----------------

static __device__ __forceinline__ void split8v(float4 u, float4 v, bf16x8& h, bf16x8& l) {
  float x[8] = {u.x, u.y, u.z, u.w, v.x, v.y, v.z, v.w};
#pragma unroll
  for (int j = 0; j < 8; ++j) {
    __bf16 hh = (__bf16)x[j];
    h[j] = hh;
    l[j] = (__bf16)(x[j] - (float)hh);
  }
}

static __device__ __forceinline__ void storev(unsigned short* p, float v) { *p = f2bf(v); }
static __device__ __forceinline__ void storev(float* p, float v) { *p = v; }

template<int NT, bool RELU, bool SCALE, typename OutT>
__global__ __launch_bounds__(512, 4)
void gemm_f32a(const float* __restrict__ A,
               const unsigned short* __restrict__ Wh, const unsigned short* __restrict__ Wl,
               const float* __restrict__ snorm, OutT* __restrict__ out, int nN) {
  __shared__ unsigned short Bh[NT * 512];   // [nt][lane][8] bf16, frag-linear
  __shared__ unsigned short Bl[NT * 512];
  const int tid  = threadIdx.x;
  const int w    = tid >> 6;            // 0..7
  const int lane = tid & 63;
  const int quad = lane >> 4;
  const int l16  = lane & 15;
  const int m0   = blockIdx.x * 128 + w * 16;   // one 16-row strip per wave

  f32x4 acc[NT];
#pragma unroll
  for (int i = 0; i < NT; ++i) acc[i] = (f32x4){0.f, 0.f, 0.f, 0.f};

  int r0 = m0 + l16;  int rc0 = (r0 < nN) ? r0 : (nN - 1);
  const float* Ap = A + (size_t)rc0 * 256 + quad * 8;

  float4 u = *(const float4*)(Ap);          // prefetch kk=0
  float4 v = *(const float4*)(Ap + 4);

  for (int kk = 0; kk < 8; ++kk) {
    __syncthreads();
    for (int ch = tid; ch < NT * 64; ch += 512) {
      int nt = ch >> 6; int L = ch & 63;
      int n  = nt * 16 + (L & 15);
      int kb = (L >> 4) * 8;
      *(int4*)(Bh + ch * 8) = *(const int4*)(Wh + n * 256 + kk * 32 + kb);
      *(int4*)(Bl + ch * 8) = *(const int4*)(Wl + n * 256 + kk * 32 + kb);
    }
    // issue next kk's A-load before the barrier: retires under barrier + MFMA
    float4 un = u, vn = v;
    if (kk < 7) {
      un = *(const float4*)(Ap + (kk + 1) * 32);
      vn = *(const float4*)(Ap + (kk + 1) * 32 + 4);
    }
    __syncthreads();
    bf16x8 ah, al;
    split8v(u, v, ah, al);
#pragma unroll
    for (int nt = 0; nt < NT; ++nt) {
      bf16x8 bh = *(const bf16x8*)(Bh + nt * 512 + lane * 8);
      bf16x8 bl = *(const bf16x8*)(Bl + nt * 512 + lane * 8);
      acc[nt] = __builtin_amdgcn_mfma_f32_16x16x32_bf16(ah, bh, acc[nt], 0, 0, 0);
      acc[nt] = __builtin_amdgcn_mfma_f32_16x16x32_bf16(al, bh, acc[nt], 0, 0, 0);
      acc[nt] = __builtin_amdgcn_mfma_f32_16x16x32_bf16(ah, bl, acc[nt], 0, 0, 0);
    }
    u = un; v = vn;
  }

  // epilogue: C/D layout col=lane&15, row=quad*4+reg
  const int N = NT * 16;
#pragma unroll
  for (int reg = 0; reg < 4; ++reg) {
    int rr0 = m0 + quad * 4 + reg;
    float s0 = 1.f;
    if (SCALE) s0 = snorm[(rr0 < nN) ? rr0 : 0];
#pragma unroll
    for (int nt = 0; nt < NT; ++nt) {
      if (rr0 < nN) {
        float v2 = acc[nt][reg];
        if (RELU) v2 = fmaxf(v2, 0.f);
        if (SCALE) v2 *= s0;
        storev(out + (size_t)rr0 * N + nt * 16 + l16, v2);
      }
    }
  }
}

// ---------------- launch ----------------

extern "C" void kernel_launch(void* const* d_in, const int* in_sizes, int n_in,
                              void* d_out, int out_size, void* d_ws, size_t ws_size,
                              hipStream_t stream) {
  const float* feat = (const float*)d_in[0];
  const int*   src  = (const int*)d_in[1];
  const int*   dst  = (const int*)d_in[2];
  const float* W0   = (const float*)d_in[3];
  const float* W1   = (const float*)d_in[4];
  const float* W2   = (const float*)d_in[5];
  const int nE = in_sizes[1];
  const int nN = in_sizes[0] / FEATS;

  char* p = (char*)d_ws;
  auto alloc = [&](size_t bytes) -> void* {
    void* r = (void*)p;
    p += (bytes + 255) & ~(size_t)255;
    return r;
  };
  unsigned* outdeg = (unsigned*)alloc((size_t)nN * 4);   // pure W-plane space
  unsigned* indeg  = (unsigned*)alloc((size_t)nN * 4);
  float*    snorm  = (float*)   alloc((size_t)nN * 4);
  float*    dnorm  = (float*)   alloc((size_t)nN * 4);
  float*    X      = (float*)   alloc((size_t)nN * 256 * 4);  // bf16 X1/F1; fp32 F2
  float*    G      = (float*)   alloc((size_t)nN * 256 * 4);  // agg buffer; P_in/P_out/H3b alias
  unsigned* excl     = (unsigned*)alloc((size_t)nN * 4);
  unsigned* partials = (unsigned*)alloc(1024 * 4);
  unsigned* row_ptr  = (unsigned*)alloc(((size_t)nN + 1) * 4);
  unsigned* edge_src = (unsigned*)alloc((size_t)nE * 4);
  // footprint < proven 220.0 MB

  unsigned short* Xb  = (unsigned short*)X;   // bf16 view (first half of X region)
  unsigned char* P_in  = (unsigned char*)G;   // u8 planes, dead before spmm layer 1
  unsigned char* P_out = P_in + (size_t)NSLICE * nN;
  unsigned short* H3b = (unsigned short*)G;   // layer-3 bf16 output (12.8MB), alias ok

  // Weight hi/lo planes (576 KB) alias the dead outdeg/indeg region (proven R9/R10)
  unsigned short* W0h = (unsigned short*)outdeg;
  unsigned short* W0l = W0h + 256 * 256;
  unsigned short* W1h = W0l + 256 * 256;
  unsigned short* W1l = W1h + 256 * 256;
  unsigned short* W2h = W1l + 256 * 256;
  unsigned short* W2l = W2h + 64 * 256;

  const int TB = 256;
  int gN  = (nN + TB - 1) / TB;
  int nb  = (nN + 1023) / 1024;
  int gRow = (nN * 64 + TB - 1) / TB;   // wave per row/node (full range)
  int gGm  = (nN + 127) / 128;          // MFMA gemm: 128 rows/block, 512 threads
  int chunk = (nE + NSLICE - 1) / NSLICE;
  dim3 gHist(NSLICE, NRANGE);

  int half  = (nN + 1) / 2;
  int gRowA = (half * 64 + TB - 1) / TB;
  int gRowB = ((nN - half) * 64 + TB - 1) / TB;

  // u8 atomic-free graph prep
  hist_u8<<<gHist, TB, 0, stream>>>(dst, P_in,  nE, nN, chunk);
  hist_u8<<<gHist, TB, 0, stream>>>(src, P_out, nE, nN, chunk);
  reduce_prefix_norms<<<gN, TB, 0, stream>>>(P_in, P_out, indeg, snorm, dnorm, nN);
  scan_blocks<<<nb, 1024, 0, stream>>>(indeg, excl, partials, nN);
  scan_partials<<<1, 1024, 0, stream>>>(partials, nb);
  finalize_rowptr<<<gN, TB, 0, stream>>>(excl, partials, row_ptr, nN, nE);
  place_u8<<<gHist, TB, 0, stream>>>(src, dst, P_in, row_ptr, edge_src, nE, nN, chunk);

  // weight splits into the dead outdeg/indeg region
  cast_w_split<<<(256 * 256 + TB - 1) / TB, TB, 0, stream>>>(W0, W0h, W0l, 256, 256);
  cast_w_split<<<(256 * 256 + TB - 1) / TB, TB, 0, stream>>>(W1, W1h, W1l, 256, 256);
  cast_w_split<<<(256 * 64  + TB - 1) / TB, TB, 0, stream>>>(W2, W2h, W2l, 256, 64);

  int total8 = nN * (FEATS / 8);
  prescale_bf16<<<(total8 + TB - 1) / TB, TB, 0, stream>>>(feat, snorm, Xb, total8);

  // layer 1: G = dn * seg_sum(Xb[src]); F1 = bf16(relu(G @ W0)*sn) -> Xb
  spmm_bf16row<<<gRowA, TB, 0, stream>>>(Xb, row_ptr, edge_src, dnorm, G, 0, half);
  spmm_bf16row<<<gRowB, TB, 0, stream>>>(Xb, row_ptr, edge_src, dnorm, G, half, nN);
  gemm_f32a<16, true, true, unsigned short><<<gGm, 512, 0, stream>>>(G, W0h, W0l, snorm, Xb, nN);
  // layer 2: bf16 gather -> G fp32; F2 = fp32 relu(G @ W1)*sn -> X
  spmm_bf16row<<<gRowA, TB, 0, stream>>>(Xb, row_ptr, edge_src, dnorm, G, 0, half);
  spmm_bf16row<<<gRowB, TB, 0, stream>>>(Xb, row_ptr, edge_src, dnorm, G, half, nN);
  gemm_f32a<16, true, true, float><<<gGm, 512, 0, stream>>>(G, W1h, W1l, snorm, X, nN);
  // layer 3: H3b = bf16(X @ W2) -> G region; out = dn * seg_sum(H3b[src]) in fp32
  gemm_f32a<4, false, false, unsigned short><<<gGm, 512, 0, stream>>>(X, W2h, W2l, nullptr, H3b, nN);
  spmm64_bf16<<<gRow, TB, 0, stream>>>(H3b, row_ptr, edge_src, dnorm, (float*)d_out, nN);
}